// Round 9
// baseline (78.269 us; speedup 1.0000x reference)
//
#include <hip/hip_runtime.h>
#include <cstddef>
#include <cstdint>

typedef __attribute__((ext_vector_type(8))) _Float16 half8;
typedef __attribute__((ext_vector_type(4))) float f32x4;

constexpr int Bsz = 2048, Tsz = 120, Ksz = 128;
constexpr float L2E = 1.44269504088896340736f;  // log2(e)
constexpr float LN2 = 0.69314718055994530942f;  // ln(2)

__device__ __forceinline__ int expbits(float x) {
  return (int)(__float_as_uint(x) >> 23) - 127;   // floor(log2 x), x > 0
}

// drain LDS ops, then block barrier; pin the scheduler so nothing drifts.
#define BAR() do {                                        \
    asm volatile("s_waitcnt lgkmcnt(0)" ::: "memory");    \
    __builtin_amdgcn_s_barrier();                         \
    __builtin_amdgcn_sched_barrier(0);                    \
  } while (0)

// 4 waves x 16 batches per block. Wave w owns states [32w,32w+32).
// Linear-space recursion: alpha*log2e = nReg + log2(P); per step
//   S = E^T . P  (2x2 MFMA chains/rti),  P' = S * exp(em) * 2^-Df,
//   Df = expbits(max_col P_prev) + 8 (delay-free, via LDS partial maxes).
// NO transcendentals on the S-dependent path: exp(em) is precomputed from
// the 2-step-old raw prefetch at step start; 2^-Df is a bit-built constant.
__global__ __launch_bounds__(256) void crf_fwd(
    const float* __restrict__ emis,   // [B,T,K]
    const int* __restrict__ tag,      // [B,T]
    const int* __restrict__ maskg,    // [B,T]
    const float* __restrict__ Tg,     // [K,K]
    float* __restrict__ nll)          // [B]
{
  __shared__ float Tst[Ksz * Ksz];                  // 64 KB transitions copy
  __shared__ __align__(16) uint2 Pb[2][16 * 32];    // P f16, dbuf, XOR swizzle
  __shared__ __align__(16) float lamp[2][16][20];   // per-(w,hi) partial maxes
  __shared__ int maskLds[Tsz * 16];                 // [t][c]

  const int tid = threadIdx.x;
  const int w = tid >> 6, lane = tid & 63;
  const int c = lane & 15, hi = lane >> 4;
  const int b0 = blockIdx.x * 16;
  const int sw2 = (c & 7) << 1;                     // swizzle in uint2 units
  const int slot = 4 * w + hi;                      // 0..15 partial slot

  const int soff = 32 * w + 4 * hi;
  const float* ep = emis + (size_t)(b0 + c) * Tsz * Ksz + soff;

  // issue t=0,1,2 emission loads early (raw)
  f32x4 a0[2], emA[2], emB[2];
  a0[0] = *(const f32x4*)(ep);
  a0[1] = *(const f32x4*)(ep + 16);
  emA[0] = *(const f32x4*)(ep + Ksz);
  emA[1] = *(const f32x4*)(ep + Ksz + 16);
  emB[0] = *(const f32x4*)(ep + 2 * Ksz);
  emB[1] = *(const f32x4*)(ep + 2 * Ksz + 16);

  // coalesced stage of transitions + masks
  {
    const f32x4* src = (const f32x4*)Tg;
    f32x4* dst = (f32x4*)Tst;
    #pragma unroll
    for (int k = 0; k < (Ksz * Ksz / 4) / 256; ++k)
      dst[tid + k * 256] = src[tid + k * 256];
  }
  for (int i = tid; i < Tsz * 16; i += 256) {
    int cc = i & 15, tt = i >> 4;
    maskLds[i] = maskg[(size_t)(b0 + cc) * Tsz + tt];
  }
  __syncthreads();

  // E^T A-fragments: A[row=32w+16rti+c][k=32m+8hi+j] = exp(T[k][row])
  half8 Ef[2][4];
  #pragma unroll
  for (int rti = 0; rti < 2; ++rti)
    #pragma unroll
    for (int m = 0; m < 4; ++m) {
      half8 v;
      #pragma unroll
      for (int j = 0; j < 8; ++j)
        v[j] = (_Float16)__expf(Tst[(32 * m + 8 * hi + j) * Ksz + (32 * w + 16 * rti + c)]);
      Ef[rti][m] = v;
    }

  // ---- prologue: cross-wave per-col max of alpha0 via lamp[1] scratch
  {
    float pm = fmaxf(fmaxf(fmaxf(a0[0][0], a0[0][1]), fmaxf(a0[0][2], a0[0][3])),
                     fmaxf(fmaxf(a0[1][0], a0[1][1]), fmaxf(a0[1][2], a0[1][3])));
    lamp[1][c][slot] = pm;
  }
  BAR();
  float nReg;
  f32x4 Pv[2];
  {
    const float* lr = &lamp[1][c][0];
    f32x4 l0 = *(const f32x4*)(lr), l1 = *(const f32x4*)(lr + 4);
    f32x4 l2 = *(const f32x4*)(lr + 8), l3 = *(const f32x4*)(lr + 12);
    f32x4 mm;
    #pragma unroll
    for (int r = 0; r < 4; ++r) mm[r] = fmaxf(fmaxf(l0[r], l1[r]), fmaxf(l2[r], l3[r]));
    float mx = fmaxf(fmaxf(mm[0], mm[1]), fmaxf(mm[2], mm[3]));
    nReg = mx * L2E;
    #pragma unroll
    for (int rti = 0; rti < 2; ++rti)
      #pragma unroll
      for (int r = 0; r < 4; ++r) Pv[rti][r] = __expf(a0[rti][r] - mx);
  }

  auto publish = [&](int wr) {
    float pl = 0.f;
    #pragma unroll
    for (int rti = 0; rti < 2; ++rti) {
      union { _Float16 h[4]; uint2 u; } pk;
      #pragma unroll
      for (int r = 0; r < 4; ++r) {
        pk.h[r] = (_Float16)Pv[rti][r];
        pl = fmaxf(pl, Pv[rti][r]);
      }
      Pb[wr][c * 32 + ((8 * w + 4 * rti + hi) ^ sw2)] = pk.u;
    }
    lamp[wr][c][slot] = pl;
  };

  publish(0);
  BAR();

  const f32x4 z = {0.f, 0.f, 0.f, 0.f};

  auto STEP = [&](int t, f32x4 (&em)[2]) {
    const int rd = (t - 1) & 1, wr = t & 1;
    const uint2* prowR = &Pb[rd][c * 32];
    // B-fragments: P[k=32m+8hi+j][col c] -- one b128 per m (idx even)
    half8 bf[4];
    #pragma unroll
    for (int m = 0; m < 4; ++m) {
      union { uint4 u4; half8 h; } rb;
      const int idx = (8 * m + 2 * hi) ^ sw2;
      rb.u4 = *(const uint4*)(&prowR[idx]);
      bf[m] = rb.h;
    }
    // Df from 16 partial maxes (no shuffles)
    const float* lr = &lamp[rd][c][0];
    f32x4 l0 = *(const f32x4*)(lr), l1 = *(const f32x4*)(lr + 4);
    f32x4 l2 = *(const f32x4*)(lr + 8), l3 = *(const f32x4*)(lr + 12);
    f32x4 mm;
    #pragma unroll
    for (int r = 0; r < 4; ++r) mm[r] = fmaxf(fmaxf(l0[r], l1[r]), fmaxf(l2[r], l3[r]));
    const float lam = fmaxf(fmaxf(mm[0], mm[1]), fmaxf(mm[2], mm[3]));
    const int Dfi = expbits(lam) + 8;
    const float s2 = __uint_as_float((uint32_t)(127 - Dfi) << 23);  // exact 2^-Df
    const int mt = maskLds[t * 16 + c];

    // eem = exp(em): raw loaded 2 steps ago -> no vmcnt stall; exp latency
    // hides under the ds_reads/MFMA. Then c2 = eem * s2 (pre-MFMA-drain).
    f32x4 eem[2];
    #pragma unroll
    for (int rti = 0; rti < 2; ++rti)
      #pragma unroll
      for (int r = 0; r < 4; ++r) eem[rti][r] = __expf(em[rti][r]);

    f32x4 acc[2];
    #pragma unroll
    for (int rti = 0; rti < 2; ++rti) {
      f32x4 aA = __builtin_amdgcn_mfma_f32_16x16x32_f16(
          Ef[rti][1], bf[1],
          __builtin_amdgcn_mfma_f32_16x16x32_f16(Ef[rti][0], bf[0], z, 0, 0, 0),
          0, 0, 0);
      f32x4 aB = __builtin_amdgcn_mfma_f32_16x16x32_f16(
          Ef[rti][3], bf[3],
          __builtin_amdgcn_mfma_f32_16x16x32_f16(Ef[rti][2], bf[2], z, 0, 0, 0),
          0, 0, 0);
      #pragma unroll
      for (int r = 0; r < 4; ++r) acc[rti][r] = aA[r] + aB[r];
    }

    // prefetch raw emis[t+2] (em regs free: eem already extracted)
    if (t + 2 < Tsz) {
      em[0] = *(const f32x4*)(ep + (size_t)(t + 2) * Ksz);
      em[1] = *(const f32x4*)(ep + (size_t)(t + 2) * Ksz + 16);
    }

    f32x4 c2[2];
    #pragma unroll
    for (int rti = 0; rti < 2; ++rti)
      #pragma unroll
      for (int r = 0; r < 4; ++r) c2[rti][r] = eem[rti][r] * s2;

    // new P (fast path: all 16 cols unmasked -- wave-uniform)
    unsigned long long bal = __ballot(mt > 0);
    if (bal == ~0ull) {
      #pragma unroll
      for (int rti = 0; rti < 2; ++rti)
        #pragma unroll
        for (int r = 0; r < 4; ++r) Pv[rti][r] = acc[rti][r] * c2[rti][r];
    } else {
      #pragma unroll
      for (int rti = 0; rti < 2; ++rti)
        #pragma unroll
        for (int r = 0; r < 4; ++r) {
          float pn = acc[rti][r] * c2[rti][r];
          float po = Pv[rti][r] * s2;
          Pv[rti][r] = (mt > 0) ? pn : po;
        }
    }
    nReg += (float)Dfi;

    publish(wr);
    BAR();
  };

  #pragma unroll 1
  for (int t = 1; t <= Tsz - 3; t += 2) {   // (1,2)...(117,118)
    STEP(t, emA);
    STEP(t + 1, emB);
  }
  STEP(Tsz - 1, emA);                       // t = 119

  // ---- final: lognorm = nReg*ln2 + log(sum P) (shared normalizer -> no max)
  {
    float ss = ((Pv[0][0] + Pv[0][1]) + (Pv[0][2] + Pv[0][3]))
             + ((Pv[1][0] + Pv[1][1]) + (Pv[1][2] + Pv[1][3]));
    lamp[1][c][slot] = ss;
  }
  BAR();
  float lognorm;
  {
    const float* lr = &lamp[1][c][0];
    f32x4 l0 = *(const f32x4*)(lr), l1 = *(const f32x4*)(lr + 4);
    f32x4 l2 = *(const f32x4*)(lr + 8), l3 = *(const f32x4*)(lr + 12);
    float tot = (((l0[0] + l0[1]) + (l0[2] + l0[3]))
              + ((l1[0] + l1[1]) + (l1[2] + l1[3])))
              + (((l2[0] + l2[1]) + (l2[2] + l2[3]))
              + ((l3[0] + l3[1]) + (l3[2] + l3[3])));
    lognorm = nReg * LN2 + __logf(tot);
  }

  // ---- score: lane (w,hi,c) -> batch c, t-chunk [8*slot, 8*slot+8)
  {
    const int* tb = tag + (size_t)(b0 + c) * Tsz;
    const float* eb2 = emis + (size_t)(b0 + c) * Tsz * Ksz;
    float sc = 0.f;
    const int t0 = 8 * slot;
    const int t1 = (t0 + 8 < Tsz) ? t0 + 8 : Tsz;
    #pragma unroll 1
    for (int t = t0; t < t1; ++t) {
      int tg0 = tb[t];
      float m0 = (float)maskLds[t * 16 + c];
      sc += eb2[(size_t)t * Ksz + tg0] * m0;
      if (t + 1 < Tsz) {
        int tg1 = tb[t + 1];
        sc += Tst[tg0 * Ksz + tg1] * m0 * (float)maskLds[(t + 1) * 16 + c];
      }
    }
    float* scb = (float*)&Pb[0][0];    // reuse as [c][16]
    scb[c * 16 + slot] = sc;
    BAR();
    if (tid < 16) {                    // w=0, hi=0, c=tid
      const float* sr = &scb[c * 16];
      float s2r = 0.f;
      #pragma unroll
      for (int s = 0; s < 16; ++s) s2r += sr[s];
      nll[b0 + c] = lognorm - s2r;
    }
  }
}

// deterministic fixed-order mean over B values
__global__ __launch_bounds__(256) void crf_reduce(
    const float* __restrict__ nll, float* __restrict__ out) {
  __shared__ float buf[256];
  float s = 0.f;
  for (int i = threadIdx.x; i < Bsz; i += 256) s += nll[i];
  buf[threadIdx.x] = s;
  __syncthreads();
  #pragma unroll
  for (int off = 128; off > 0; off >>= 1) {
    if (threadIdx.x < off) buf[threadIdx.x] += buf[threadIdx.x + off];
    __syncthreads();
  }
  if (threadIdx.x == 0) out[0] = buf[0] / (float)Bsz;
}

extern "C" void kernel_launch(void* const* d_in, const int* in_sizes, int n_in,
                              void* d_out, int out_size, void* d_ws, size_t ws_size,
                              hipStream_t stream) {
  const float* emissions   = (const float*)d_in[0];
  const int*   tag_ids     = (const int*)d_in[1];
  const int*   mask        = (const int*)d_in[2];
  const float* transitions = (const float*)d_in[3];

  float* nll = (float*)d_ws;  // 2048 floats

  crf_fwd<<<Bsz / 16, 256, 0, stream>>>(emissions, tag_ids, mask, transitions, nll);
  crf_reduce<<<1, 256, 0, stream>>>(nll, (float*)d_out);
}